// Round 2
// baseline (340.165 us; speedup 1.0000x reference)
//
#include <hip/hip_runtime.h>

// BilateralSliceApply: grid [N,2,16,16,8] f32, guide [N,2048,2048] f32,
// input [N,3,2048,2048] f32 -> out [N,1,2048,2048] f32
// out = a*(x0+x1+x2)+b where (a,b) = trilinear slice of grid at
// (y=h/2047*15, x=w/2047*15, z=(guide+1)*0.5*7).

namespace {
constexpr int N_IMG = 4;
constexpr int GH = 16, GW = 16, GD = 8;
constexpr int H = 2048, W = 2048;
constexpr int P = H * W;            // pixels per image
constexpr int SP = GH * GW * GD;    // 2048 grid cells per channel
constexpr int BX = 512;             // blocks per image
constexpr int TPB = 256;
constexpr int PXT = 4;              // pixels per thread per iteration
}

__global__ __launch_bounds__(TPB) void bsa_kernel(
    const float* __restrict__ grid,   // [N,2,GH,GW,GD]
    const float* __restrict__ guide,  // [N,H,W]
    const float* __restrict__ input,  // [N,3,H,W]
    float* __restrict__ out)          // [N,H,W]
{
    // LDS layout: [y][x][z][c] so (z,c) pairs are contiguous float2s.
    __shared__ float lds[SP * 2 + 4];
    const int n = blockIdx.y;
    const int tid = threadIdx.x;

    const float* gsrc = grid + (size_t)n * (2 * SP);
#pragma unroll
    for (int k = 0; k < SP / TPB; ++k) {
        const int i = tid + k * TPB;          // spatial index y*128+x*8+z
        lds[2 * i + 0] = gsrc[i];             // c = 0 (multiplier a)
        lds[2 * i + 1] = gsrc[SP + i];        // c = 1 (offset b)
    }
    if (tid < 4) lds[SP * 2 + tid] = 0.0f;    // safety pad
    __syncthreads();

    const float2* __restrict__ L = reinterpret_cast<const float2*>(lds);

    const float* __restrict__ gu  = guide + (size_t)n * P;
    const float* __restrict__ in0 = input + (size_t)n * 3 * P;
    const float* __restrict__ in1 = in0 + P;
    const float* __restrict__ in2 = in1 + P;
    float*       __restrict__ op  = out + (size_t)n * P;

    for (int p0 = (blockIdx.x * TPB + tid) * PXT; p0 < P; p0 += BX * TPB * PXT) {
        const int h  = p0 >> 11;          // row (W = 2048)
        const int wb = p0 & (W - 1);      // col of first pixel (multiple of 4)

        const float4 gv = *reinterpret_cast<const float4*>(gu  + p0);
        const float4 c0 = *reinterpret_cast<const float4*>(in0 + p0);
        const float4 c1 = *reinterpret_cast<const float4*>(in1 + p0);
        const float4 c2 = *reinterpret_cast<const float4*>(in2 + p0);

        // y interpolation (shared by all 4 pixels)
        const float iy  = (float)h / 2047.0f * 15.0f;
        const float fyf = floorf(iy);
        const float fy  = iy - fyf;
        int y0 = (int)fyf; y0 = y0 < 0 ? 0 : (y0 > GH - 1 ? GH - 1 : y0);
        const int y1 = (y0 + 1 > GH - 1) ? GH - 1 : y0 + 1;
        const float wy0 = 1.0f - fy, wy1 = fy;

        const float gvals[PXT] = {gv.x, gv.y, gv.z, gv.w};
        const float xsum [PXT] = {c0.x + c1.x + c2.x, c0.y + c1.y + c2.y,
                                  c0.z + c1.z + c2.z, c0.w + c1.w + c2.w};
        float rr[PXT];
#pragma unroll
        for (int j = 0; j < PXT; ++j) {
            // x interpolation
            const float ix  = (float)(wb + j) / 2047.0f * 15.0f;
            const float fxf = floorf(ix);
            const float fx  = ix - fxf;
            int x0 = (int)fxf; x0 = x0 < 0 ? 0 : (x0 > GW - 1 ? GW - 1 : x0);
            const int x1 = (x0 + 1 > GW - 1) ? GW - 1 : x0 + 1;
            const float wx0 = 1.0f - fx, wx1 = fx;

            // z interpolation from guide value
            const float iz  = (gvals[j] + 1.0f) * 0.5f * 7.0f;
            const float fzf = floorf(iz);
            const float fz  = iz - fzf;
            int z0 = (int)fzf; z0 = z0 < 0 ? 0 : (z0 > GD - 1 ? GD - 1 : z0);
            const int z1 = (z0 + 1 > GD - 1) ? GD - 1 : z0 + 1;
            const float wz0 = 1.0f - fz, wz1 = fz;

            float a = 0.0f, b = 0.0f;
            {
                const int base = (y0 * GW + x0) * GD;
                const float2 v0 = L[base + z0], v1 = L[base + z1];
                const float wyx = wy0 * wx0;
                a += wyx * (wz0 * v0.x + wz1 * v1.x);
                b += wyx * (wz0 * v0.y + wz1 * v1.y);
            }
            {
                const int base = (y0 * GW + x1) * GD;
                const float2 v0 = L[base + z0], v1 = L[base + z1];
                const float wyx = wy0 * wx1;
                a += wyx * (wz0 * v0.x + wz1 * v1.x);
                b += wyx * (wz0 * v0.y + wz1 * v1.y);
            }
            {
                const int base = (y1 * GW + x0) * GD;
                const float2 v0 = L[base + z0], v1 = L[base + z1];
                const float wyx = wy1 * wx0;
                a += wyx * (wz0 * v0.x + wz1 * v1.x);
                b += wyx * (wz0 * v0.y + wz1 * v1.y);
            }
            {
                const int base = (y1 * GW + x1) * GD;
                const float2 v0 = L[base + z0], v1 = L[base + z1];
                const float wyx = wy1 * wx1;
                a += wyx * (wz0 * v0.x + wz1 * v1.x);
                b += wyx * (wz0 * v0.y + wz1 * v1.y);
            }

            rr[j] = a * xsum[j] + b;
        }

        const float4 res = make_float4(rr[0], rr[1], rr[2], rr[3]);
        *reinterpret_cast<float4*>(op + p0) = res;
    }
}

extern "C" void kernel_launch(void* const* d_in, const int* in_sizes, int n_in,
                              void* d_out, int out_size, void* d_ws, size_t ws_size,
                              hipStream_t stream) {
    const float* grid  = (const float*)d_in[0];   // [4,2,16,16,8]
    const float* guide = (const float*)d_in[1];   // [4,2048,2048]
    const float* input = (const float*)d_in[2];   // [4,3,2048,2048]
    float* out = (float*)d_out;                   // [4,1,2048,2048]

    dim3 grd(BX, N_IMG);
    dim3 blk(TPB);
    bsa_kernel<<<grd, blk, 0, stream>>>(grid, guide, input, out);
}

// Round 3
// 317.434 us; speedup vs baseline: 1.0716x; 1.0716x over previous
//
#include <hip/hip_runtime.h>

// BilateralSliceApply: grid [N,2,16,16,8] f32, guide [N,2048,2048] f32,
// input [N,3,2048,2048] f32 -> out [N,1,2048,2048] f32
// out = a*(x0+x1+x2)+b where (a,b) = trilinear slice of grid at
// (y=h/2047*15, x=w/2047*15, z=(guide+1)*0.5*7).

typedef float f32x4 __attribute__((ext_vector_type(4)));

namespace {
constexpr int N_IMG = 4;
constexpr int GH = 16, GW = 16, GD = 8;
constexpr int H = 2048, W = 2048;
constexpr int P = H * W;             // pixels per image
constexpr int SP = GH * GW * GD;     // 2048 grid cells per channel
constexpr int BX = 512;              // blocks per image
constexpr int TPB = 256;
constexpr int PXT = 4;               // pixels per thread per iteration
constexpr int STRIDE = BX * TPB * PXT;  // 524288
constexpr int ITERS = P / STRIDE;       // 8 (exact)
constexpr float XSC = 15.0f / 2047.0f;  // 1-ulp-equiv of (w/2047)*15; safe at
                                        // w in {0,2047} since there x1==x0.
}

__global__ __launch_bounds__(TPB) void bsa_kernel(
    const float* __restrict__ grid,   // [N,2,GH,GW,GD]
    const float* __restrict__ guide,  // [N,H,W]
    const float* __restrict__ input,  // [N,3,H,W]
    float* __restrict__ out)          // [N,H,W]
{
    // LDS layout: [y][x][z] of float2 {a,b} so one ds_read_b64 per corner.
    __shared__ float2 L[SP];
    const int n = blockIdx.y;
    const int tid = threadIdx.x;

    const float* gsrc = grid + (size_t)n * (2 * SP);
#pragma unroll
    for (int k = 0; k < SP / TPB; ++k) {
        const int i = tid + k * TPB;                    // y*128 + x*8 + z
        L[i] = make_float2(gsrc[i], gsrc[SP + i]);      // {a, b}
    }
    __syncthreads();

    const float* __restrict__ gu  = guide + (size_t)n * P;
    const float* __restrict__ in0 = input + (size_t)n * 3 * P;
    const float* __restrict__ in1 = in0 + P;
    const float* __restrict__ in2 = in1 + P;
    float*       __restrict__ op  = out + (size_t)n * P;

    const int base = (blockIdx.x * TPB + tid) * PXT;

#pragma unroll 2
    for (int it = 0; it < ITERS; ++it) {
        const int p  = base + it * STRIDE;
        const int h  = p >> 11;          // row (W = 2048)
        const int wb = p & (W - 1);      // col of first pixel (multiple of 4)

        const f32x4 gv = __builtin_nontemporal_load((const f32x4*)(gu  + p));
        const f32x4 c0 = __builtin_nontemporal_load((const f32x4*)(in0 + p));
        const f32x4 c1 = __builtin_nontemporal_load((const f32x4*)(in1 + p));
        const f32x4 c2 = __builtin_nontemporal_load((const f32x4*)(in2 + p));

        // y interpolation (shared by the 4 pixels; ix,iy in [0,15] always)
        const float iy  = (float)h * XSC;
        const float fyf = floorf(iy);
        const float fy  = iy - fyf;
        const int   y0  = (int)fyf;
        const int   y1  = (y0 + 1 > GH - 1) ? GH - 1 : y0 + 1;
        const float wy0 = 1.0f - fy, wy1 = fy;
        const int   yb0 = y0 * (GW * GD), yb1 = y1 * (GW * GD);

        float rr[PXT];
#pragma unroll
        for (int j = 0; j < PXT; ++j) {
            // x interpolation
            const float ix  = (float)(wb + j) * XSC;
            const float fxf = floorf(ix);
            const float fx  = ix - fxf;
            const int   x0  = (int)fxf;
            const int   x1  = (x0 + 1 > GW - 1) ? GW - 1 : x0 + 1;
            const float wx0 = 1.0f - fx, wx1 = fx;
            const int   xb0 = x0 * GD, xb1 = x1 * GD;

            // z interpolation from guide value (guide in [0,1) -> iz in [3.5,7))
            const float iz  = (gv[j] + 1.0f) * 3.5f;
            const float fzf = floorf(iz);
            const float fz  = iz - fzf;
            int z0 = (int)fzf; z0 = z0 < 0 ? 0 : (z0 > GD - 1 ? GD - 1 : z0);
            const int   z1  = (z0 + 1 > GD - 1) ? GD - 1 : z0 + 1;
            const float wz0 = 1.0f - fz, wz1 = fz;

            float a, b;
            {
                const float2 v0 = L[yb0 + xb0 + z0], v1 = L[yb0 + xb0 + z1];
                const float ww = wy0 * wx0;
                a = ww * fmaf(wz0, v0.x, wz1 * v1.x);
                b = ww * fmaf(wz0, v0.y, wz1 * v1.y);
            }
            {
                const float2 v0 = L[yb0 + xb1 + z0], v1 = L[yb0 + xb1 + z1];
                const float ww = wy0 * wx1;
                a = fmaf(ww, fmaf(wz0, v0.x, wz1 * v1.x), a);
                b = fmaf(ww, fmaf(wz0, v0.y, wz1 * v1.y), b);
            }
            {
                const float2 v0 = L[yb1 + xb0 + z0], v1 = L[yb1 + xb0 + z1];
                const float ww = wy1 * wx0;
                a = fmaf(ww, fmaf(wz0, v0.x, wz1 * v1.x), a);
                b = fmaf(ww, fmaf(wz0, v0.y, wz1 * v1.y), b);
            }
            {
                const float2 v0 = L[yb1 + xb1 + z0], v1 = L[yb1 + xb1 + z1];
                const float ww = wy1 * wx1;
                a = fmaf(ww, fmaf(wz0, v0.x, wz1 * v1.x), a);
                b = fmaf(ww, fmaf(wz0, v0.y, wz1 * v1.y), b);
            }

            const float xs = (c0[j] + c1[j]) + c2[j];
            rr[j] = fmaf(a, xs, b);
        }

        const f32x4 res = {rr[0], rr[1], rr[2], rr[3]};
        __builtin_nontemporal_store(res, (f32x4*)(op + p));
    }
}

extern "C" void kernel_launch(void* const* d_in, const int* in_sizes, int n_in,
                              void* d_out, int out_size, void* d_ws, size_t ws_size,
                              hipStream_t stream) {
    const float* grid  = (const float*)d_in[0];   // [4,2,16,16,8]
    const float* guide = (const float*)d_in[1];   // [4,2048,2048]
    const float* input = (const float*)d_in[2];   // [4,3,2048,2048]
    float* out = (float*)d_out;                   // [4,1,2048,2048]

    dim3 grd(BX, N_IMG);
    dim3 blk(TPB);
    bsa_kernel<<<grd, blk, 0, stream>>>(grid, guide, input, out);
}